// Round 1
// 483.581 us; speedup vs baseline: 1.0828x; 1.0828x over previous
//
#include <hip/hip_runtime.h>
#include <hip/hip_bf16.h>

typedef __attribute__((ext_vector_type(8))) short short8;
typedef __attribute__((ext_vector_type(4))) short short4v;
typedef __attribute__((ext_vector_type(4))) float floatx4;

#define M_DIM 8192
#define N_DIM 4096
#define K_DIM 4096
#define BK 64

__device__ __constant__ float NF4_TAB[16] = {
    -1.0f, -0.6961928009986877f, -0.5250730514526367f, -0.39491748809814453f,
    -0.28444138169288635f, -0.18477343022823334f, -0.09105003625154495f, 0.0f,
    0.07958029955625534f, 0.16093020141124725f, 0.24611230194568634f,
    0.33791524171829224f, 0.44070982933044434f, 0.5626170039176941f,
    0.7229568362236023f, 1.0f};

// W_eff[n][k] = NF4[code]*scale + 2*sum_r loraB[n][r]*loraA[r][k], as bf16.
__global__ __launch_bounds__(256)
void dequant_lora_kernel(const int* __restrict__ codes,
                         const float* __restrict__ scales,
                         const float* __restrict__ la,
                         const float* __restrict__ lb,
                         short4v* __restrict__ W) {
    __shared__ float tab[16];
    if (threadIdx.x < 16) tab[threadIdx.x] = NF4_TAB[threadIdx.x];
    __syncthreads();

    const int kb = blockIdx.x & 3;                 // 4 k-blocks of 1024
    const int n0 = (blockIdx.x >> 2) << 4;         // 16 n-rows per block
    const int k0 = kb * 1024 + threadIdx.x * 4;

    float4 a[16];
#pragma unroll
    for (int r = 0; r < 16; r++)
        a[r] = *(const float4*)(la + (size_t)r * K_DIM + k0);

#pragma unroll 4
    for (int i = 0; i < 16; i++) {
        const int n = n0 + i;
        int4 c = *(const int4*)(codes + (size_t)n * K_DIM + k0);
        float s = scales[(n << 6) + (k0 >> 6)];
        const float* bp = lb + (n << 4);           // wave-uniform -> s_load
        float acc0 = 0.f, acc1 = 0.f, acc2 = 0.f, acc3 = 0.f;
#pragma unroll
        for (int r = 0; r < 16; r++) {
            float br = bp[r];
            acc0 += br * a[r].x;
            acc1 += br * a[r].y;
            acc2 += br * a[r].z;
            acc3 += br * a[r].w;
        }
        union { short4v v; __hip_bfloat16 h[4]; } u;
        u.h[0] = __float2bfloat16(tab[c.x] * s + 2.0f * acc0);
        u.h[1] = __float2bfloat16(tab[c.y] * s + 2.0f * acc1);
        u.h[2] = __float2bfloat16(tab[c.z] * s + 2.0f * acc2);
        u.h[3] = __float2bfloat16(tab[c.w] * s + 2.0f * acc3);
        W[((size_t)n * K_DIM + k0) >> 2] = u.v;
    }
}

// fp32 -> bf16 cast, 8 elements per thread
__global__ void cast_x_kernel(const float* __restrict__ x,
                              short8* __restrict__ xb) {
    int g = blockIdx.x * blockDim.x + threadIdx.x;
    const float4* xp = (const float4*)(x + (size_t)g * 8);
    float4 v0 = xp[0], v1 = xp[1];
    union { short8 v; __hip_bfloat16 h[8]; } u;
    u.h[0] = __float2bfloat16(v0.x);
    u.h[1] = __float2bfloat16(v0.y);
    u.h[2] = __float2bfloat16(v0.z);
    u.h[3] = __float2bfloat16(v0.w);
    u.h[4] = __float2bfloat16(v1.x);
    u.h[5] = __float2bfloat16(v1.y);
    u.h[6] = __float2bfloat16(v1.z);
    u.h[7] = __float2bfloat16(v1.w);
    xb[g] = u.v;
}

#define GL2LDS(gsrc, ldst)                                                   \
    __builtin_amdgcn_global_load_lds(                                        \
        (const __attribute__((address_space(1))) void*)(gsrc),               \
        (__attribute__((address_space(3))) void*)(ldst), 16, 0, 0)

// ---------------------------------------------------------------------------
// 256x256 tile, BK=64, 8 waves (2M x 4N), double-buffered LDS (128 KiB),
// 8-phase schedule: counted vmcnt(4) once per K-tile (never 0 in main loop),
// 1 half-tile (2 x global_load_lds) staged per phase, setprio around MFMA.
// Swizzle: 16B-block XOR with (row&7), applied on pre-swizzled global source
// (linear global_load_lds dest) and on ds_read addresses. C = A * B^T.
// ---------------------------------------------------------------------------

// per-phase staging of one half-tile: 2 x global_load_lds x 512 threads
#define STAGE_A(D, H, T) do {                                                 \
    GL2LDS(gA0 + (size_t)((H) * 128) * K_DIM + (T) * BK,                      \
           ldsA + (D) * 32768 + (H) * 16384 + ldsw);                          \
    GL2LDS(gA0 + (size_t)((H) * 128 + 64) * K_DIM + (T) * BK,                 \
           ldsA + (D) * 32768 + (H) * 16384 + 8192 + ldsw);                   \
} while (0)

#define STAGE_B(D, H, T) do {                                                 \
    GL2LDS(gB0 + (size_t)((H) * 128) * K_DIM + (T) * BK,                      \
           ldsB + (D) * 32768 + (H) * 16384 + ldsw);                          \
    GL2LDS(gB0 + (size_t)((H) * 128 + 64) * K_DIM + (T) * BK,                 \
           ldsB + (D) * 32768 + (H) * 16384 + 8192 + ldsw);                   \
} while (0)

#define MFMA_Q(AF, BF, MB, NB) do {                                           \
    _Pragma("unroll") for (int mi_ = 0; mi_ < 4; mi_++)                       \
    _Pragma("unroll") for (int ni_ = 0; ni_ < 2; ni_++)                       \
    _Pragma("unroll") for (int ks_ = 0; ks_ < 2; ks_++)                       \
        acc[(MB) + mi_][(NB) + ni_] =                                         \
            __builtin_amdgcn_mfma_f32_16x16x32_bf16(                          \
                AF[mi_][ks_], BF[ni_][ks_], acc[(MB) + mi_][(NB) + ni_],      \
                0, 0, 0);                                                     \
} while (0)

#define LGKM0 asm volatile("s_waitcnt lgkmcnt(0)" ::: "memory")
#define VM4   asm volatile("s_waitcnt vmcnt(4)" ::: "memory")
#define VM0   asm volatile("s_waitcnt vmcnt(0)" ::: "memory")
#define VMNONE do {} while (0)

// One K-tile = 4 phases. Quadrant order (mq,nq): P1(0,0) P2(1,0) P3(0,1) P4(1,1)
// Staging slots: P1: B0(T+1)  P2: B1(T+1)  P3: A0(T+2)  P4: A1(T+2)
// (each target region's last reader finished >=1 barrier before the issue)
#define TILE(T, D, DOB, DOA, VM) do {                                         \
    short8 af0[4][2], af1[4][2], bf0[2][2], bf1[2][2];                        \
    /* P1: read af0(8) + bf0(4); stage B0(T+1) */                             \
    _Pragma("unroll") for (int mi_ = 0; mi_ < 4; mi_++) {                     \
        int o_ = (D) * 32768 + aoff + mi_ * 2048;                             \
        af0[mi_][0] = *(const short8*)(ldsA + o_);                            \
        af0[mi_][1] = *(const short8*)(ldsA + (o_ ^ 64));                     \
    }                                                                         \
    _Pragma("unroll") for (int ni_ = 0; ni_ < 2; ni_++) {                     \
        int o_ = (D) * 32768 + boff + ni_ * 2048;                             \
        bf0[ni_][0] = *(const short8*)(ldsB + o_);                            \
        bf0[ni_][1] = *(const short8*)(ldsB + (o_ ^ 64));                     \
    }                                                                         \
    if (DOB) STAGE_B((D) ^ 1, 0, (T) + 1);                                    \
    __builtin_amdgcn_s_barrier();                                             \
    LGKM0;                                                                    \
    __builtin_amdgcn_s_setprio(1);                                            \
    MFMA_Q(af0, bf0, 0, 0);                                                   \
    __builtin_amdgcn_s_setprio(0);                                            \
    __builtin_amdgcn_s_barrier();                                             \
    /* P2: read af1(8); stage B1(T+1) */                                      \
    _Pragma("unroll") for (int mi_ = 0; mi_ < 4; mi_++) {                     \
        int o_ = (D) * 32768 + aoff + 8192 + mi_ * 2048;                      \
        af1[mi_][0] = *(const short8*)(ldsA + o_);                            \
        af1[mi_][1] = *(const short8*)(ldsA + (o_ ^ 64));                     \
    }                                                                         \
    if (DOB) STAGE_B((D) ^ 1, 1, (T) + 1);                                    \
    __builtin_amdgcn_s_barrier();                                             \
    LGKM0;                                                                    \
    __builtin_amdgcn_s_setprio(1);                                            \
    MFMA_Q(af1, bf0, 4, 0);                                                   \
    __builtin_amdgcn_s_setprio(0);                                            \
    __builtin_amdgcn_s_barrier();                                             \
    /* P3: read bf1(4); stage A0(T+2) */                                      \
    _Pragma("unroll") for (int ni_ = 0; ni_ < 2; ni_++) {                     \
        int o_ = (D) * 32768 + boff + 4096 + ni_ * 2048;                      \
        bf1[ni_][0] = *(const short8*)(ldsB + o_);                            \
        bf1[ni_][1] = *(const short8*)(ldsB + (o_ ^ 64));                     \
    }                                                                         \
    if (DOA) STAGE_A((D), 0, (T) + 2);                                        \
    __builtin_amdgcn_s_barrier();                                             \
    LGKM0;                                                                    \
    __builtin_amdgcn_s_setprio(1);                                            \
    MFMA_Q(af0, bf1, 0, 2);                                                   \
    __builtin_amdgcn_s_setprio(0);                                            \
    __builtin_amdgcn_s_barrier();                                             \
    /* P4: stage A1(T+2); counted vmcnt, once per K-tile */                   \
    if (DOA) STAGE_A((D), 1, (T) + 2);                                        \
    VM;                                                                       \
    __builtin_amdgcn_s_barrier();                                             \
    __builtin_amdgcn_s_setprio(1);                                            \
    MFMA_Q(af1, bf1, 4, 2);                                                   \
    __builtin_amdgcn_s_setprio(0);                                            \
    __builtin_amdgcn_s_barrier();                                             \
} while (0)

__global__ __launch_bounds__(512, 2)
void gemm_bt_kernel(const __hip_bfloat16* __restrict__ A,
                    const __hip_bfloat16* __restrict__ B,
                    float* __restrict__ C) {
    __shared__ __align__(16) char lds[131072];
    char* ldsA = (char*)lds;            // [2][256][64] bf16
    char* ldsB = (char*)lds + 65536;    // [2][256][64] bf16

    const int tid = threadIdx.x;
    const int wave = tid >> 6;
    const int lane = tid & 63;
    const int q = lane >> 4;
    const int t16 = lane & 15;
    const int wm = wave >> 2;           // 0..1  -> 128 rows of M
    const int wn = wave & 3;            // 0..3  -> 64 cols of N

    // bijective XCD-aware swizzle (512 blocks, 512 % 8 == 0)
    const int bid = blockIdx.x;
    const int swz = ((bid & 7) << 6) | (bid >> 3);
    const int bm0 = (swz >> 4) << 8;
    const int bn0 = (swz & 15) << 8;

    // ds_read per-lane base byte offsets within one 32 KiB buffer
    const int sw = (q ^ (t16 & 7)) << 4;
    const int aoff = (wm * 128 + t16) * 128 + sw;
    const int boff = (wn * 64 + t16) * 128 + sw;

    // staging: thread covers LDS linear bytes (j*512+tid)*16, j = 0,1
    // row = (j*512+tid)>>3, phys 16B-block = tid&7, logical = phys^(row&7)
    const int r0 = tid >> 3;
    const int c0 = ((tid & 7) ^ (r0 & 7)) << 3;
    const __hip_bfloat16* gA0 = A + (size_t)(bm0 + r0) * K_DIM + c0;
    const __hip_bfloat16* gB0 = B + (size_t)(bn0 + r0) * K_DIM + c0;
    const int ldsw = wave << 10;        // wave-uniform LDS base (+lane*16 by HW)

    floatx4 acc[8][4] = {};

    // prologue: tile0 all 4 half-tiles, tile1 A halves; drain tile0, keep A(1)
    STAGE_A(0, 0, 0); STAGE_A(0, 1, 0);
    STAGE_B(0, 0, 0); STAGE_B(0, 1, 0);
    STAGE_A(1, 0, 1); STAGE_A(1, 1, 1);
    VM4;
    __builtin_amdgcn_s_barrier();

#pragma unroll 1
    for (int tp = 0; tp < 31; ++tp) {
        const int t2 = tp << 1;
        TILE(t2, 0, 1, 1, VM4);
        TILE(t2 + 1, 1, 1, 1, VM4);
    }
    TILE(62, 0, 1, 0, VM0);
    TILE(63, 1, 0, 0, VMNONE);

    // C/D layout: col = lane&15, row = (lane>>4)*4 + reg (m89/m91 verified)
#pragma unroll
    for (int mi = 0; mi < 8; mi++) {
        int row0 = bm0 + wm * 128 + mi * 16 + q * 4;
#pragma unroll
        for (int ni = 0; ni < 4; ni++) {
            int col = bn0 + wn * 64 + ni * 16 + t16;
            float* cp = C + (size_t)row0 * N_DIM + col;
#pragma unroll
            for (int r = 0; r < 4; r++) cp[(size_t)r * N_DIM] = acc[mi][ni][r];
        }
    }
}

extern "C" void kernel_launch(void* const* d_in, const int* in_sizes, int n_in,
                              void* d_out, int out_size, void* d_ws,
                              size_t ws_size, hipStream_t stream) {
    const float* x = (const float*)d_in[0];
    const int* codes = (const int*)d_in[1];
    const float* scales = (const float*)d_in[2];
    const float* loraA = (const float*)d_in[3];
    const float* loraB = (const float*)d_in[4];
    float* out = (float*)d_out;

    char* ws = (char*)d_ws;
    __hip_bfloat16* xb = (__hip_bfloat16*)ws;                    // 64 MiB
    __hip_bfloat16* Wb = (__hip_bfloat16*)(ws + 67108864);       // 32 MiB

    dequant_lora_kernel<<<dim3(4 * (N_DIM / 16)), dim3(256), 0, stream>>>(
        codes, scales, loraA, loraB, (short4v*)Wb);
    cast_x_kernel<<<dim3((M_DIM * (K_DIM / 8)) / 256), dim3(256), 0, stream>>>(
        x, (short8*)xb);
    gemm_bt_kernel<<<dim3(512), dim3(512), 0, stream>>>(xb, Wb, out);
}